// Round 3
// baseline (583.292 us; speedup 1.0000x reference)
//
#include <hip/hip_runtime.h>
#include <hip/hip_bf16.h>

// Problem constants (fixed by the reference)
#define B_DIM 8192
#define K_DIM 4096
#define N_DIM 4096
#define GROUP 128
#define NG    (K_DIM / GROUP)   // 32 groups
#define INV_SQRT_GROUP 0.08838834764831845f  // 1/sqrt(128)

using bf16x8 = __attribute__((ext_vector_type(8))) short;  // 8 bf16 (4 VGPRs)
using f32x4  = __attribute__((ext_vector_type(4))) float;  // 4 fp32 acc

// round-to-nearest-even f32 -> bf16
__device__ inline unsigned short f2bf(float f) {
    union { float f; unsigned u; } v; v.f = f;
    unsigned r = v.u + 0x7fffu + ((v.u >> 16) & 1u);
    return (unsigned short)(r >> 16);
}

#define GLOAD_LDS16(gp, lp)                                                   \
    __builtin_amdgcn_global_load_lds(                                         \
        (__attribute__((address_space(1))) void*)(gp),                        \
        (__attribute__((address_space(3))) void*)(lp), 16, 0, 0)

// raw barrier (no vmcnt drain!) with compiler memory fences on both sides
#define BAR()                                                                 \
    {                                                                         \
        asm volatile("" ::: "memory");                                        \
        __builtin_amdgcn_s_barrier();                                         \
        asm volatile("" ::: "memory");                                        \
    }
#define LGKM0()  asm volatile("s_waitcnt lgkmcnt(0)" ::: "memory")
#define VMCNT(n) asm volatile("s_waitcnt vmcnt(" #n ")" ::: "memory")
#define PRIO(p)  __builtin_amdgcn_s_setprio(p)

// ---------------------------------------------------------------------------
// Kernel 1: cast x (B,K) f32 -> bf16, 8 elems/thread, 16B stores
// ---------------------------------------------------------------------------
__global__ __launch_bounds__(256) void cast_x_kernel(
    const float* __restrict__ x, unsigned short* __restrict__ xb, size_t n8)
{
    size_t i = (size_t)blockIdx.x * blockDim.x + threadIdx.x;
    if (i >= n8) return;
    const float4* xp = (const float4*)x;
    float4 a = xp[2 * i];
    float4 b = xp[2 * i + 1];
    union { unsigned short s[8]; uint4 v; } pk;
    pk.s[0] = f2bf(a.x); pk.s[1] = f2bf(a.y); pk.s[2] = f2bf(a.z); pk.s[3] = f2bf(a.w);
    pk.s[4] = f2bf(b.x); pk.s[5] = f2bf(b.y); pk.s[6] = f2bf(b.z); pk.s[7] = f2bf(b.w);
    ((uint4*)xb)[i] = pk.v;
}

// ---------------------------------------------------------------------------
// Kernel 1b: Rt[g][k][j] = bf16(R[g][j][k])  (1 MiB out; reads coalesced over k)
// ---------------------------------------------------------------------------
__global__ __launch_bounds__(256) void cast_rot_kernel(
    const float* __restrict__ rot, unsigned short* __restrict__ Rt)
{
    const int g = blockIdx.x;
    const float* Rg = rot + (size_t)g * GROUP * GROUP;
    unsigned short* Rtg = Rt + (size_t)g * GROUP * GROUP;
    for (int e = threadIdx.x; e < 128 * 32; e += 256) {
        int j = e >> 5, kc = (e & 31) * 4;
        float4 v = *(const float4*)(Rg + (size_t)j * 128 + kc);
        Rtg[(size_t)(kc + 0) * 128 + j] = f2bf(v.x);
        Rtg[(size_t)(kc + 1) * 128 + j] = f2bf(v.y);
        Rtg[(size_t)(kc + 2) * 128 + j] = f2bf(v.z);
        Rtg[(size_t)(kc + 3) * 128 + j] = f2bf(v.w);
    }
}

// ---------------------------------------------------------------------------
// Kernel 2: V[n, g*128+k] = (norms[n,g]/sqrt(128)) * sum_j cb[idx[n,g*128+j]] * R[g,j,k]
// Epilogue now transposes through w_lds (reused) so V is written with 16B
// stores, 16 lanes covering one full 256B row-slice (was: 2B scatter).
// ---------------------------------------------------------------------------
__global__ __launch_bounds__(256) void prep_v_kernel(
    const int*   __restrict__ indices,   // (N, K)
    const float* __restrict__ codebook,  // (16,)
    const float* __restrict__ norms,     // (N, G)
    const unsigned short* __restrict__ Rt, // (G, 128, 128) bf16, k-major
    unsigned short* __restrict__ Vout)   // (N, K) bf16
{
    const int g  = blockIdx.y;
    const int n0 = blockIdx.x * 128;
    const int tid = threadIdx.x;

    // row stride 136 ushort = 272B = 17*16B -> every row base is 16B-aligned
    __shared__ __attribute__((aligned(16))) unsigned short w_lds[128][136];
    __shared__ float s_lds[128];
    __shared__ float cb_lds[16];

    if (tid < 16)  cb_lds[tid] = codebook[tid];
    if (tid < 128) s_lds[tid] = norms[(size_t)(n0 + tid) * NG + g] * INV_SQRT_GROUP;
    __syncthreads();

    for (int e = tid; e < 128 * 16; e += 256) {
        const int nl = e >> 4, jc = e & 15;
        const float s = s_lds[nl];
        const int4* ip = (const int4*)(indices + (size_t)(n0 + nl) * K_DIM + g * GROUP + jc * 8);
        int4 i0 = ip[0];
        int4 i1 = ip[1];
        union { unsigned short h[8]; uint4 v; } pk;
        pk.h[0] = f2bf(cb_lds[i0.x] * s); pk.h[1] = f2bf(cb_lds[i0.y] * s);
        pk.h[2] = f2bf(cb_lds[i0.z] * s); pk.h[3] = f2bf(cb_lds[i0.w] * s);
        pk.h[4] = f2bf(cb_lds[i1.x] * s); pk.h[5] = f2bf(cb_lds[i1.y] * s);
        pk.h[6] = f2bf(cb_lds[i1.z] * s); pk.h[7] = f2bf(cb_lds[i1.w] * s);
        *(uint4*)&w_lds[nl][jc * 8] = pk.v;
    }
    __syncthreads();

    const int lane = tid & 63;
    const int wv   = tid >> 6;
    const int l15  = lane & 15;
    const int quad = lane >> 4;
    const int wn = (wv >> 1) * 64;   // n offset within tile
    const int wk = (wv & 1) * 64;    // k offset within tile

    const unsigned short* Rtg = Rt + (size_t)g * GROUP * GROUP;

    f32x4 acc[4][4] = {};

    for (int js = 0; js < 4; ++js) {
        const int jo = js * 32 + quad * 8;
        bf16x8 aF[4], bF[4];
        for (int mi = 0; mi < 4; ++mi)
            aF[mi] = *(const bf16x8*)&w_lds[wn + mi * 16 + l15][jo];
        for (int ni = 0; ni < 4; ++ni) {
            const int k = wk + ni * 16 + l15;
            bF[ni] = *(const bf16x8*)(Rtg + (size_t)k * 128 + jo);
        }
        for (int mi = 0; mi < 4; ++mi)
            for (int ni = 0; ni < 4; ++ni)
                acc[mi][ni] = __builtin_amdgcn_mfma_f32_16x16x32_bf16(
                    aF[mi], bF[ni], acc[mi][ni], 0, 0, 0);
    }

    // All w_lds reads done (per-wave waitcnts precede MFMA use); join waves,
    // then reuse w_lds as the V-tile transpose buffer.
    __syncthreads();

    // C/D layout: row = quad*4 + r (n), col = l15 (k)
    for (int mi = 0; mi < 4; ++mi) {
        const int nl = wn + mi * 16 + quad * 4;
        for (int ni = 0; ni < 4; ++ni) {
            const int kl = wk + ni * 16 + l15;
            for (int r = 0; r < 4; ++r)
                w_lds[nl + r][kl] = f2bf(acc[mi][ni][r]);
        }
    }
    __syncthreads();

    // coalesced write-out: 16 lanes cover one 256B row-slice; 8 passes.
    {
        const int rlo = tid >> 4;          // 0..15
        const int col = (tid & 15) * 8;    // 0..120
        for (int pass = 0; pass < 8; ++pass) {
            const int row = pass * 16 + rlo;
            uint4 v = *(const uint4*)&w_lds[row][col];
            *(uint4*)(Vout + (size_t)(n0 + row) * K_DIM + g * GROUP + col) = v;
        }
    }
}

// ---------------------------------------------------------------------------
// Kernel 3: C (8192x4096 f32) = Xb (8192x4096 bf16) @ V^T (V is 4096x4096 bf16)
//
// 256x256 tile, BK=64, 8 waves (2M x 4N), 512 threads, LDS 128 KiB
// double-buffered. 4 phases per K-tile, DEEP prefetch (all staging targets
// tile t+2, issued in P3/P4 into the buffer whose reads completed):
//   P1: ds_read aF(m0-3)+bF(n0-1)                  | BAR lgkm0 16xMFMA BAR
//   P2: ds_read bF(n2-3)                           | BAR lgkm0 16xMFMA BAR
//   P3: ds_read aF(m4-7) | stage B(t+2)h0 -> buf b | BAR lgkm0 16xMFMA BAR
//   P4: stage B(t+2)h1 + A(t+2) -> buf b | BAR 16xMFMA vmcnt(8) BAR
// Legality: B-reads of buf[b] complete by P2-end barrier (each wave's lgkm0
// precedes its P2 MFMA) -> P3 may stage B(t+2) into b_lds[b]. A-reads of
// buf[b] complete by P3-end barrier -> P4 may stage A(t+2) into a_lds[b].
// Steady-state ledger at the end-of-P4 vmcnt: queue (oldest first) =
// [B(t+1)x4, A(t+1)x4, B(t+2)x4, A(t+2)x4] -> vmcnt(8) forces tile t+1
// fully landed with tile t+2 still in flight. Every load gets a full
// K-tile (~5000 cyc) of latency cover. Drain to 0 only at t==62.
// XOR chunk swizzle: phys chunk = logical ^ (row&7) on the GLOBAL source
// (global_load_lds dest must be linear wave-uniform base + lane*16).
// XCD-aware block swizzle: 512 wgs % 8 == 0 -> chunked bijective map.
// ---------------------------------------------------------------------------
template <int GRP, int NLO>
__device__ __forceinline__ void mfma_quad(f32x4 (&acc)[8][4],
                                          const bf16x8 (&aF)[4][2],
                                          const bf16x8 (&bF)[4][2])
{
#pragma unroll
    for (int mi = 0; mi < 4; ++mi)
#pragma unroll
        for (int nn = 0; nn < 2; ++nn)
#pragma unroll
            for (int kh = 0; kh < 2; ++kh)
                acc[GRP * 4 + mi][NLO + nn] = __builtin_amdgcn_mfma_f32_16x16x32_bf16(
                    aF[mi][kh], bF[NLO + nn][kh], acc[GRP * 4 + mi][NLO + nn], 0, 0, 0);
}

__global__ __launch_bounds__(512) void gemm256_kernel(
    const unsigned short* __restrict__ A,   // (B_DIM, K_DIM) bf16
    const unsigned short* __restrict__ Bm,  // (N_DIM, K_DIM) bf16
    float* __restrict__ C)                  // (B_DIM, N_DIM) f32
{
    const int tid = threadIdx.x;

    // XCD-aware chunked swizzle (8 XCDs; 512 wgs, 512%8==0 -> bijective).
    // Each XCD owns 64 consecutive swz ids = 4 full M-panel rows.
    const int flat = blockIdx.y * gridDim.x + blockIdx.x;   // 0..511
    const int swz  = (flat & 7) * 64 + (flat >> 3);
    const int n0 = (swz & 15) * 256;
    const int m0 = (swz >> 4) * 256;

    __shared__ __attribute__((aligned(16))) unsigned short a_lds[2 * 256 * 64];
    __shared__ __attribute__((aligned(16))) unsigned short b_lds[2 * 256 * 64];

    const int lane = tid & 63;
    const int wv   = tid >> 6;    // 0..7
    const int l15  = lane & 15;
    const int quad = lane >> 4;
    const int wm   = wv >> 2;     // 0..1 -> 128-row M half
    const int wn   = wv & 3;      // 0..3 -> 64-col N quarter

    // staging: 2048 chunks of 16B per operand, 4 passes of 512 threads.
    // physical slot c holds logical chunk (c&7)^((c>>3)&7) of row c>>3.
    int rr[4], ko[4], lb[4];
#pragma unroll
    for (int p = 0; p < 4; ++p) {
        int c = tid + 512 * p;
        rr[p] = c >> 3;
        ko[p] = ((c & 7) ^ ((c >> 3) & 7)) * 8;
        lb[p] = (tid & ~63) + 512 * p;   // wave-uniform dest chunk base
    }

    // fragment-read physical chunk offsets (elems)
    const int koh0 = ((0 * 4 + quad) ^ (l15 & 7)) * 8;
    const int koh1 = ((1 * 4 + quad) ^ (l15 & 7)) * 8;
    const int aBase = (wm * 128 + l15) * 64;
    const int bBase = (wn * 64 + l15) * 64;

    f32x4 acc[8][4] = {};
    bf16x8 aF[4][2], bF[4][2];

#define STAGE_A(bb, kt, p)                                                    \
    GLOAD_LDS16(A + (size_t)(m0 + rr[p]) * K_DIM + (size_t)(kt) * 64 + ko[p], \
                a_lds + (bb) * 16384 + lb[p] * 8)
#define STAGE_B(bb, kt, p)                                                    \
    GLOAD_LDS16(Bm + (size_t)(n0 + rr[p]) * K_DIM + (size_t)(kt) * 64 + ko[p],\
                b_lds + (bb) * 16384 + lb[p] * 8)

    // prologue: tile0 -> buf0, tile1 -> buf1 (16 loads); wait tile0 only.
#pragma unroll
    for (int p = 0; p < 4; ++p) STAGE_A(0, 0, p);
#pragma unroll
    for (int p = 0; p < 4; ++p) STAGE_B(0, 0, p);
#pragma unroll
    for (int p = 0; p < 4; ++p) STAGE_A(1, 1, p);
#pragma unroll
    for (int p = 0; p < 4; ++p) STAGE_B(1, 1, p);
    VMCNT(8);   // tile0 fully landed; tile1 still in flight
    BAR();

    for (int t = 0; t < 64; ++t) {
        const int b = t & 1;
        const int boff = b * 16384;

        // ---- P1: aF(m-grp0) + bF(n0,n1) ----------------------------------
#pragma unroll
        for (int mi = 0; mi < 4; ++mi) {
            aF[mi][0] = *(const bf16x8*)&a_lds[boff + aBase + mi * 1024 + koh0];
            aF[mi][1] = *(const bf16x8*)&a_lds[boff + aBase + mi * 1024 + koh1];
        }
#pragma unroll
        for (int nn = 0; nn < 2; ++nn) {
            bF[nn][0] = *(const bf16x8*)&b_lds[boff + bBase + nn * 1024 + koh0];
            bF[nn][1] = *(const bf16x8*)&b_lds[boff + bBase + nn * 1024 + koh1];
        }
        BAR(); LGKM0();
        PRIO(1); mfma_quad<0, 0>(acc, aF, bF); PRIO(0);
        BAR();

        // ---- P2: bF(n2,n3) -----------------------------------------------
#pragma unroll
        for (int nn = 2; nn < 4; ++nn) {
            bF[nn][0] = *(const bf16x8*)&b_lds[boff + bBase + nn * 1024 + koh0];
            bF[nn][1] = *(const bf16x8*)&b_lds[boff + bBase + nn * 1024 + koh1];
        }
        BAR(); LGKM0();
        PRIO(1); mfma_quad<0, 2>(acc, aF, bF); PRIO(0);
        BAR();

        // ---- P3: aF(m-grp1); stage B(t+2) half0 -> buf b -----------------
#pragma unroll
        for (int mi = 0; mi < 4; ++mi) {
            aF[mi][0] = *(const bf16x8*)&a_lds[boff + aBase + 4096 + mi * 1024 + koh0];
            aF[mi][1] = *(const bf16x8*)&a_lds[boff + aBase + 4096 + mi * 1024 + koh1];
        }
        if (t + 2 < 64) { STAGE_B(b, t + 2, 0); STAGE_B(b, t + 2, 1); }
        BAR(); LGKM0();
        PRIO(1); mfma_quad<1, 0>(acc, aF, bF); PRIO(0);
        BAR();

        // ---- P4: stage B(t+2) half1 + A(t+2) -> buf b; vmcnt gate --------
        if (t + 2 < 64) {
            STAGE_B(b, t + 2, 2); STAGE_B(b, t + 2, 3);
#pragma unroll
            for (int p = 0; p < 4; ++p) STAGE_A(b, t + 2, p);
        }
        BAR();
        PRIO(1); mfma_quad<1, 2>(acc, aF, bF); PRIO(0);
        if (t < 62)       { VMCNT(8); }   // tile t+1 landed; t+2 may fly
        else if (t == 62) { VMCNT(0); }   // last tile: full drain
        BAR();
    }

    // epilogue: row = quad*4 + r (m), col = l15 (n)
#pragma unroll
    for (int mi = 0; mi < 8; ++mi) {
        int m = m0 + wm * 128 + mi * 16 + quad * 4;
#pragma unroll
        for (int ni = 0; ni < 4; ++ni) {
            int n = n0 + wn * 64 + ni * 16 + l15;
            float* dst = C + (size_t)m * N_DIM + n;
#pragma unroll
            for (int r = 0; r < 4; ++r)
                dst[(size_t)r * N_DIM] = acc[mi][ni][r];
        }
    }
#undef STAGE_A
#undef STAGE_B
}

// ---------------------------------------------------------------------------
extern "C" void kernel_launch(void* const* d_in, const int* in_sizes, int n_in,
                              void* d_out, int out_size, void* d_ws, size_t ws_size,
                              hipStream_t stream)
{
    const float* x        = (const float*)d_in[0];  // (B, K)
    const int*   indices  = (const int*)d_in[1];    // (N, K)
    const float* codebook = (const float*)d_in[2];  // (16,)
    const float* norms    = (const float*)d_in[3];  // (N, G)
    const float* rot      = (const float*)d_in[4];  // (G, 128, 128)
    float* out            = (float*)d_out;          // (B, N)

    unsigned short* Rt = (unsigned short*)d_ws;                       // 1 MiB
    unsigned short* Xb = Rt + (size_t)NG * GROUP * GROUP;             // 64 MiB
    unsigned short* V  = Xb + (size_t)B_DIM * K_DIM;                  // 32 MiB

    // 1) cast x to bf16; cast+transpose rotations to bf16
    {
        size_t n8 = (size_t)B_DIM * K_DIM / 8;
        cast_x_kernel<<<dim3((unsigned)(n8 / 256)), dim3(256), 0, stream>>>(x, Xb, n8);
        cast_rot_kernel<<<dim3(NG), dim3(256), 0, stream>>>(rot, Rt);
    }
    // 2) build rotated/dequantized weights V
    {
        dim3 grid(N_DIM / 128, NG);
        prep_v_kernel<<<grid, dim3(256), 0, stream>>>(indices, codebook, norms, Rt, V);
    }
    // 3) out = Xb @ V^T  (256^2 deep-prefetch counted-vmcnt schedule)
    {
        dim3 grid(N_DIM / 256, B_DIM / 256);
        gemm256_kernel<<<grid, dim3(512), 0, stream>>>(Xb, V, out);
    }
}

// Round 4
// 534.853 us; speedup vs baseline: 1.0906x; 1.0906x over previous
//
#include <hip/hip_runtime.h>
#include <hip/hip_bf16.h>

// Problem constants (fixed by the reference)
#define B_DIM 8192
#define K_DIM 4096
#define N_DIM 4096
#define GROUP 128
#define NG    (K_DIM / GROUP)   // 32 groups
#define INV_SQRT_GROUP 0.08838834764831845f  // 1/sqrt(128)

using bf16x8 = __attribute__((ext_vector_type(8))) short;  // 8 bf16 (4 VGPRs)
using f32x4  = __attribute__((ext_vector_type(4))) float;  // 4 fp32 acc

// round-to-nearest-even f32 -> bf16
__device__ inline unsigned short f2bf(float f) {
    union { float f; unsigned u; } v; v.f = f;
    unsigned r = v.u + 0x7fffu + ((v.u >> 16) & 1u);
    return (unsigned short)(r >> 16);
}

#define GLOAD_LDS16(gp, lp)                                                   \
    __builtin_amdgcn_global_load_lds(                                         \
        (__attribute__((address_space(1))) void*)(gp),                        \
        (__attribute__((address_space(3))) void*)(lp), 16, 0, 0)

// raw barrier (no vmcnt drain!) with compiler memory fences on both sides
#define BAR()                                                                 \
    {                                                                         \
        asm volatile("" ::: "memory");                                        \
        __builtin_amdgcn_s_barrier();                                         \
        asm volatile("" ::: "memory");                                        \
    }
#define LGKM0()  asm volatile("s_waitcnt lgkmcnt(0)" ::: "memory")
#define VMCNT(n) asm volatile("s_waitcnt vmcnt(" #n ")" ::: "memory")
#define PRIO(p)  __builtin_amdgcn_s_setprio(p)

// ---------------------------------------------------------------------------
// Kernel 1: cast x (B,K) f32 -> bf16, 8 elems/thread, 16B stores
// ---------------------------------------------------------------------------
__global__ __launch_bounds__(256) void cast_x_kernel(
    const float* __restrict__ x, unsigned short* __restrict__ xb, size_t n8)
{
    size_t i = (size_t)blockIdx.x * blockDim.x + threadIdx.x;
    if (i >= n8) return;
    const float4* xp = (const float4*)x;
    float4 a = xp[2 * i];
    float4 b = xp[2 * i + 1];
    union { unsigned short s[8]; uint4 v; } pk;
    pk.s[0] = f2bf(a.x); pk.s[1] = f2bf(a.y); pk.s[2] = f2bf(a.z); pk.s[3] = f2bf(a.w);
    pk.s[4] = f2bf(b.x); pk.s[5] = f2bf(b.y); pk.s[6] = f2bf(b.z); pk.s[7] = f2bf(b.w);
    ((uint4*)xb)[i] = pk.v;
}

// ---------------------------------------------------------------------------
// Kernel 1b: Rt[g][k][j] = bf16(R[g][j][k])  (1 MiB out; reads coalesced over k)
// ---------------------------------------------------------------------------
__global__ __launch_bounds__(256) void cast_rot_kernel(
    const float* __restrict__ rot, unsigned short* __restrict__ Rt)
{
    const int g = blockIdx.x;
    const float* Rg = rot + (size_t)g * GROUP * GROUP;
    unsigned short* Rtg = Rt + (size_t)g * GROUP * GROUP;
    for (int e = threadIdx.x; e < 128 * 32; e += 256) {
        int j = e >> 5, kc = (e & 31) * 4;
        float4 v = *(const float4*)(Rg + (size_t)j * 128 + kc);
        Rtg[(size_t)(kc + 0) * 128 + j] = f2bf(v.x);
        Rtg[(size_t)(kc + 1) * 128 + j] = f2bf(v.y);
        Rtg[(size_t)(kc + 2) * 128 + j] = f2bf(v.z);
        Rtg[(size_t)(kc + 3) * 128 + j] = f2bf(v.w);
    }
}

// ---------------------------------------------------------------------------
// Kernel 2: V[n, g*128+k] = (norms[n,g]/sqrt(128)) * sum_j cb[idx[n,g*128+j]] * R[g,j,k]
// Epilogue transposes through w_lds (reused) so V is written with 16B stores.
// ---------------------------------------------------------------------------
__global__ __launch_bounds__(256) void prep_v_kernel(
    const int*   __restrict__ indices,   // (N, K)
    const float* __restrict__ codebook,  // (16,)
    const float* __restrict__ norms,     // (N, G)
    const unsigned short* __restrict__ Rt, // (G, 128, 128) bf16, k-major
    unsigned short* __restrict__ Vout)   // (N, K) bf16
{
    const int g  = blockIdx.y;
    const int n0 = blockIdx.x * 128;
    const int tid = threadIdx.x;

    // row stride 136 ushort = 272B = 17*16B -> every row base is 16B-aligned
    __shared__ __attribute__((aligned(16))) unsigned short w_lds[128][136];
    __shared__ float s_lds[128];
    __shared__ float cb_lds[16];

    if (tid < 16)  cb_lds[tid] = codebook[tid];
    if (tid < 128) s_lds[tid] = norms[(size_t)(n0 + tid) * NG + g] * INV_SQRT_GROUP;
    __syncthreads();

    for (int e = tid; e < 128 * 16; e += 256) {
        const int nl = e >> 4, jc = e & 15;
        const float s = s_lds[nl];
        const int4* ip = (const int4*)(indices + (size_t)(n0 + nl) * K_DIM + g * GROUP + jc * 8);
        int4 i0 = ip[0];
        int4 i1 = ip[1];
        union { unsigned short h[8]; uint4 v; } pk;
        pk.h[0] = f2bf(cb_lds[i0.x] * s); pk.h[1] = f2bf(cb_lds[i0.y] * s);
        pk.h[2] = f2bf(cb_lds[i0.z] * s); pk.h[3] = f2bf(cb_lds[i0.w] * s);
        pk.h[4] = f2bf(cb_lds[i1.x] * s); pk.h[5] = f2bf(cb_lds[i1.y] * s);
        pk.h[6] = f2bf(cb_lds[i1.z] * s); pk.h[7] = f2bf(cb_lds[i1.w] * s);
        *(uint4*)&w_lds[nl][jc * 8] = pk.v;
    }
    __syncthreads();

    const int lane = tid & 63;
    const int wv   = tid >> 6;
    const int l15  = lane & 15;
    const int quad = lane >> 4;
    const int wn = (wv >> 1) * 64;   // n offset within tile
    const int wk = (wv & 1) * 64;    // k offset within tile

    const unsigned short* Rtg = Rt + (size_t)g * GROUP * GROUP;

    f32x4 acc[4][4] = {};

    for (int js = 0; js < 4; ++js) {
        const int jo = js * 32 + quad * 8;
        bf16x8 aF[4], bF[4];
        for (int mi = 0; mi < 4; ++mi)
            aF[mi] = *(const bf16x8*)&w_lds[wn + mi * 16 + l15][jo];
        for (int ni = 0; ni < 4; ++ni) {
            const int k = wk + ni * 16 + l15;
            bF[ni] = *(const bf16x8*)(Rtg + (size_t)k * 128 + jo);
        }
        for (int mi = 0; mi < 4; ++mi)
            for (int ni = 0; ni < 4; ++ni)
                acc[mi][ni] = __builtin_amdgcn_mfma_f32_16x16x32_bf16(
                    aF[mi], bF[ni], acc[mi][ni], 0, 0, 0);
    }

    // All w_lds reads done (per-wave waitcnts precede MFMA use); join waves,
    // then reuse w_lds as the V-tile transpose buffer.
    __syncthreads();

    // C/D layout: row = quad*4 + r (n), col = l15 (k)
    for (int mi = 0; mi < 4; ++mi) {
        const int nl = wn + mi * 16 + quad * 4;
        for (int ni = 0; ni < 4; ++ni) {
            const int kl = wk + ni * 16 + l15;
            for (int r = 0; r < 4; ++r)
                w_lds[nl + r][kl] = f2bf(acc[mi][ni][r]);
        }
    }
    __syncthreads();

    // coalesced write-out: 16 lanes cover one 256B row-slice; 8 passes.
    {
        const int rlo = tid >> 4;          // 0..15
        const int col = (tid & 15) * 8;    // 0..120
        for (int pass = 0; pass < 8; ++pass) {
            const int row = pass * 16 + rlo;
            uint4 v = *(const uint4*)&w_lds[row][col];
            *(uint4*)(Vout + (size_t)(n0 + row) * K_DIM + g * GROUP + col) = v;
        }
    }
}

// ---------------------------------------------------------------------------
// Kernel 3: C (8192x4096 f32) = Xb (8192x4096 bf16) @ V^T (V is 4096x4096 bf16)
//
// 256x256 tile, BK=64, 8 waves (2M x 4N), 512 threads, LDS 128 KiB
// double-buffered. R2-proven fine-interleave schedule (m196: coarse/2-deep
// staging HURTS; this spreads 2 loads into P1/P2 and 4 into P4):
//   P1: ds_read aF(m0-3)+bF(n0-1) | stage B(t+1)h0 | BAR lgkm0 16xMFMA BAR
//   P2: ds_read bF(n2-3)          | stage B(t+1)h1 | BAR lgkm0 16xMFMA BAR
//   P3: ds_read aF(m4-7)          |                | BAR lgkm0 16xMFMA BAR
//   P4: stage A(t+2) (4)          | BAR 16xMFMA vmcnt(4) BAR
// Ledger at P4 vmcnt (oldest first): [A(t+1)4, B(t+1)4, A(t+2)4] ->
// vmcnt(4) forces tile t+1 landed, A(t+2) stays in flight. Drain @t==62.
// XOR chunk swizzle: phys chunk = logical ^ (row&7) on the GLOBAL source
// (global_load_lds dest must be linear wave-uniform base + lane*16).
// No XCD swizzle: working set is L3-resident (T1 costs ~2% there, m160).
// Epilogue: per-mi LDS transpose (f32, stride 260 -> 2-way=free banking),
// then float4 stores: 16 lanes = 256B contiguous per segment.
// ---------------------------------------------------------------------------
template <int GRP, int NLO>
__device__ __forceinline__ void mfma_quad(f32x4 (&acc)[8][4],
                                          const bf16x8 (&aF)[4][2],
                                          const bf16x8 (&bF)[4][2])
{
#pragma unroll
    for (int mi = 0; mi < 4; ++mi)
#pragma unroll
        for (int nn = 0; nn < 2; ++nn)
#pragma unroll
            for (int kh = 0; kh < 2; ++kh)
                acc[GRP * 4 + mi][NLO + nn] = __builtin_amdgcn_mfma_f32_16x16x32_bf16(
                    aF[mi][kh], bF[NLO + nn][kh], acc[GRP * 4 + mi][NLO + nn], 0, 0, 0);
}

__global__ __launch_bounds__(512) void gemm256_kernel(
    const unsigned short* __restrict__ A,   // (B_DIM, K_DIM) bf16
    const unsigned short* __restrict__ Bm,  // (N_DIM, K_DIM) bf16
    float* __restrict__ C)                  // (B_DIM, N_DIM) f32
{
    const int tid = threadIdx.x;
    const int n0 = blockIdx.x * 256;
    const int m0 = blockIdx.y * 256;

    __shared__ __attribute__((aligned(16))) unsigned short a_lds[2 * 256 * 64];
    __shared__ __attribute__((aligned(16))) unsigned short b_lds[2 * 256 * 64];

    const int lane = tid & 63;
    const int wv   = tid >> 6;    // 0..7
    const int l15  = lane & 15;
    const int quad = lane >> 4;
    const int wm   = wv >> 2;     // 0..1 -> 128-row M half
    const int wn   = wv & 3;      // 0..3 -> 64-col N quarter

    // staging: 2048 chunks of 16B per operand, 4 passes of 512 threads.
    // physical slot c holds logical chunk (c&7)^((c>>3)&7) of row c>>3.
    int rr[4], ko[4], lb[4];
#pragma unroll
    for (int p = 0; p < 4; ++p) {
        int c = tid + 512 * p;
        rr[p] = c >> 3;
        ko[p] = ((c & 7) ^ ((c >> 3) & 7)) * 8;
        lb[p] = (tid & ~63) + 512 * p;   // wave-uniform dest chunk base
    }

    // fragment-read physical chunk offsets (elems)
    const int koh0 = ((0 * 4 + quad) ^ (l15 & 7)) * 8;
    const int koh1 = ((1 * 4 + quad) ^ (l15 & 7)) * 8;
    const int aBase = (wm * 128 + l15) * 64;
    const int bBase = (wn * 64 + l15) * 64;

    f32x4 acc[8][4] = {};
    bf16x8 aF[4][2], bF[4][2];

#define STAGE_A(bb, kt, p)                                                    \
    GLOAD_LDS16(A + (size_t)(m0 + rr[p]) * K_DIM + (size_t)(kt) * 64 + ko[p], \
                a_lds + (bb) * 16384 + lb[p] * 8)
#define STAGE_B(bb, kt, p)                                                    \
    GLOAD_LDS16(Bm + (size_t)(n0 + rr[p]) * K_DIM + (size_t)(kt) * 64 + ko[p],\
                b_lds + (bb) * 16384 + lb[p] * 8)

    // prologue: tile0 (A+B) -> buf0; tile1 A-halves -> buf1.  12 loads deep.
#pragma unroll
    for (int p = 0; p < 4; ++p) STAGE_A(0, 0, p);
#pragma unroll
    for (int p = 0; p < 4; ++p) STAGE_B(0, 0, p);
#pragma unroll
    for (int p = 0; p < 4; ++p) STAGE_A(1, 1, p);
    VMCNT(4);   // tile0 fully landed (4 newest = tile1 A still in flight)
    BAR();

    for (int t = 0; t < 64; ++t) {
        const int b = t & 1;
        const int boff = b * 16384;

        // ---- P1: aF(m-grp0) + bF(n0,n1); stage (t+1) B-half0 -------------
#pragma unroll
        for (int mi = 0; mi < 4; ++mi) {
            aF[mi][0] = *(const bf16x8*)&a_lds[boff + aBase + mi * 1024 + koh0];
            aF[mi][1] = *(const bf16x8*)&a_lds[boff + aBase + mi * 1024 + koh1];
        }
#pragma unroll
        for (int nn = 0; nn < 2; ++nn) {
            bF[nn][0] = *(const bf16x8*)&b_lds[boff + bBase + nn * 1024 + koh0];
            bF[nn][1] = *(const bf16x8*)&b_lds[boff + bBase + nn * 1024 + koh1];
        }
        if (t + 1 < 64) { STAGE_B(b ^ 1, t + 1, 0); STAGE_B(b ^ 1, t + 1, 1); }
        BAR(); LGKM0();
        PRIO(1); mfma_quad<0, 0>(acc, aF, bF); PRIO(0);
        BAR();

        // ---- P2: bF(n2,n3); stage (t+1) B-half1 --------------------------
#pragma unroll
        for (int nn = 2; nn < 4; ++nn) {
            bF[nn][0] = *(const bf16x8*)&b_lds[boff + bBase + nn * 1024 + koh0];
            bF[nn][1] = *(const bf16x8*)&b_lds[boff + bBase + nn * 1024 + koh1];
        }
        if (t + 1 < 64) { STAGE_B(b ^ 1, t + 1, 2); STAGE_B(b ^ 1, t + 1, 3); }
        BAR(); LGKM0();
        PRIO(1); mfma_quad<0, 2>(acc, aF, bF); PRIO(0);
        BAR();

        // ---- P3: aF(m-grp1) ----------------------------------------------
#pragma unroll
        for (int mi = 0; mi < 4; ++mi) {
            aF[mi][0] = *(const bf16x8*)&a_lds[boff + aBase + 4096 + mi * 1024 + koh0];
            aF[mi][1] = *(const bf16x8*)&a_lds[boff + aBase + 4096 + mi * 1024 + koh1];
        }
        BAR(); LGKM0();
        PRIO(1); mfma_quad<1, 0>(acc, aF, bF); PRIO(0);
        BAR();

        // ---- P4: stage (t+2) A both halves; counted vmcnt gate -----------
        if (t + 2 < 64) {
#pragma unroll
            for (int p = 0; p < 4; ++p) STAGE_A(b, t + 2, p);
        }
        BAR();
        PRIO(1); mfma_quad<1, 2>(acc, aF, bF); PRIO(0);
        if (t < 62)       { VMCNT(4); }   // tile t+1 landed; (t+2) A may fly
        else if (t == 62) { VMCNT(0); }   // last tile: full drain
        BAR();
    }

    // ---- epilogue: coalesced C store via LDS transpose --------------------
    // 8 passes (one mi each). Wave writes its 16x64 f32 slice into an LDS
    // tile [32][260] (rows: wm*16 + quad*4 + r; stride 260 f32 -> quads land
    // 16 banks apart = 2-way = free). Then 512 threads store 32 rows x 256
    // cols as float4: 16 consecutive lanes = 256B contiguous.
    {
        float* ct = (float*)a_lds;   // 32*260*4 = 33,280 B <= 64 KiB
        const int trow = tid >> 4;   // 0..31
        const int tc16 = tid & 15;   // 0..15
#pragma unroll
        for (int p = 0; p < 8; ++p) {
            BAR();   // previous pass's reads done before overwrite
#pragma unroll
            for (int ni = 0; ni < 4; ++ni) {
                const int col = wn * 64 + ni * 16 + l15;
#pragma unroll
                for (int r = 0; r < 4; ++r) {
                    const int jrow = wm * 16 + quad * 4 + r;
                    ct[jrow * 260 + col] = acc[p][ni][r];
                }
            }
            BAR();
            // store 32 rows x 256 cols; row trow maps to C row
            // m0 + (trow>>4)*128 + p*16 + (trow&15)
            const int m = m0 + (trow >> 4) * 128 + p * 16 + (trow & 15);
            float* dst = C + (size_t)m * N_DIM + n0;
            const float* src = ct + trow * 260;
#pragma unroll
            for (int s = 0; s < 4; ++s) {
                const int cc = (tc16 + 16 * s) * 4;
                *(float4*)&dst[cc] = *(const float4*)&src[cc];
            }
        }
    }
#undef STAGE_A
#undef STAGE_B
}

// ---------------------------------------------------------------------------
extern "C" void kernel_launch(void* const* d_in, const int* in_sizes, int n_in,
                              void* d_out, int out_size, void* d_ws, size_t ws_size,
                              hipStream_t stream)
{
    const float* x        = (const float*)d_in[0];  // (B, K)
    const int*   indices  = (const int*)d_in[1];    // (N, K)
    const float* codebook = (const float*)d_in[2];  // (16,)
    const float* norms    = (const float*)d_in[3];  // (N, G)
    const float* rot      = (const float*)d_in[4];  // (G, 128, 128)
    float* out            = (float*)d_out;          // (B, N)

    unsigned short* Rt = (unsigned short*)d_ws;                       // 1 MiB
    unsigned short* Xb = Rt + (size_t)NG * GROUP * GROUP;             // 64 MiB
    unsigned short* V  = Xb + (size_t)B_DIM * K_DIM;                  // 32 MiB

    // 1) cast x to bf16; cast+transpose rotations to bf16
    {
        size_t n8 = (size_t)B_DIM * K_DIM / 8;
        cast_x_kernel<<<dim3((unsigned)(n8 / 256)), dim3(256), 0, stream>>>(x, Xb, n8);
        cast_rot_kernel<<<dim3(NG), dim3(256), 0, stream>>>(rot, Rt);
    }
    // 2) build rotated/dequantized weights V
    {
        dim3 grid(N_DIM / 128, NG);
        prep_v_kernel<<<grid, dim3(256), 0, stream>>>(indices, codebook, norms, Rt, V);
    }
    // 3) out = Xb @ V^T  (256^2 fine-interleave counted-vmcnt schedule)
    {
        dim3 grid(N_DIM / 256, B_DIM / 256);
        gemm256_kernel<<<grid, dim3(512), 0, stream>>>(Xb, V, out);
    }
}